// Round 3
// baseline (415.022 us; speedup 1.0000x reference)
//
#include <hip/hip_runtime.h>

#define Nn    8192
#define FIN   256
#define FOUTc 128
#define MAXN  512   // degree ~ Binom(8192,0.01): mean 82, row max ~125 << 512

typedef float f32x4 __attribute__((ext_vector_type(4)));

// ---- Stage 1: x' = x@W + bias (materialized, 4 MB -> L2-resident), fused with
//      s_src = x'·phi_src, s_dst = x'·phi_dst. One wave per 8 rows: W row read as
//      float2/lane (coalesced, L2-hot, reused 8x), x via wave-uniform scalar loads. ----
__global__ __launch_bounds__(256) void k_xp(const float* __restrict__ x,
                                            const float* __restrict__ w,
                                            const float* __restrict__ bias,
                                            const float* __restrict__ phi,
                                            float* __restrict__ xp,
                                            float* __restrict__ s_src,
                                            float* __restrict__ s_dst)
{
    const int wave = blockIdx.x * 4 + (threadIdx.x >> 6);   // 256 blocks x 4 waves = 1024
    const int lane = threadIdx.x & 63;
    const int row0 = wave * 8;

    const float2 bv = ((const float2*)bias)[lane];
    const float2 ps = ((const float2*)phi)[lane];
    const float2 pd = ((const float2*)(phi + FOUTc))[lane];

    const float* xr = x + (size_t)row0 * FIN;
    float2 acc[8];
#pragma unroll
    for (int r = 0; r < 8; r++) acc[r] = make_float2(0.f, 0.f);

#pragma unroll 4
    for (int k = 0; k < FIN; k++) {
        const float2 wv = ((const float2*)(w + (size_t)k * FOUTc))[lane];
#pragma unroll
        for (int r = 0; r < 8; r++) {
            const float xv = xr[r * FIN + k];            // wave-uniform (scalar) load
            acc[r].x = fmaf(xv, wv.x, acc[r].x);
            acc[r].y = fmaf(xv, wv.y, acc[r].y);
        }
    }

#pragma unroll
    for (int r = 0; r < 8; r++) {
        const float2 h = make_float2(acc[r].x + bv.x, acc[r].y + bv.y);
        ((float2*)(xp + (size_t)(row0 + r) * FOUTc))[lane] = h;
        float a = h.x * ps.x + h.y * ps.y;
        float b = h.x * pd.x + h.y * pd.y;
#pragma unroll
        for (int off = 32; off > 0; off >>= 1) {
            a += __shfl_down(a, off, 64);
            b += __shfl_down(b, off, 64);
        }
        if (lane == 0) { s_src[row0 + r] = a; s_dst[row0 + r] = b; }
    }
}

// ---- Stage 2 (256 threads/block, 4 waves -> 8 blocks/CU): nt-prefetch adj row ->
//      compaction -> WAVE-0-ONLY softmax (pure shfl reductions, no cross-wave trees)
//      -> h[i][o] = inv * sum_n w_n * x'[j_n][o] with 2 groups x 4 chains.
//      exp(NEG_INF - m) == 0 in fp32 => sparse softmax exact; lrelu monotone =>
//      m = lrelu(s_src[i] + max_j s_dst[j]); self-loop guarantees l >= 1.
//      bias folded into x' (softmax weights sum to 1). ----
__global__ __launch_bounds__(256) void k_agg(const float* __restrict__ adj,
                                             const float* __restrict__ xp,
                                             const float* __restrict__ s_src,
                                             const float* __restrict__ s_dst,
                                             float* __restrict__ out)
{
    __shared__ int   nbr[MAXN];
    __shared__ float wts[MAXN];
    __shared__ float hp[2][FOUTc];
    __shared__ float sinv;
    __shared__ int   cnt;

    const int tid = threadIdx.x;
    const int i = blockIdx.x;
    if (tid == 0) cnt = 0;
    __syncthreads();

    // Phase 1a: nontemporal prefetch of the full 32KB row (8 x float4 per thread).
    const f32x4* arow4 = (const f32x4*)(adj + (size_t)i * Nn);
    f32x4 buf[8];
#pragma unroll
    for (int t = 0; t < 8; t++) buf[t] = __builtin_nontemporal_load(arow4 + t * 256 + tid);

    // Phase 1b: compact nonzero columns (+ self-loop). Branch body is index-store only.
#pragma unroll
    for (int t = 0; t < 8; t++) {
        const int j0 = (t * 256 + tid) * 4;
#pragma unroll
        for (int p = 0; p < 4; p++) {
            const int j = j0 + p;
            if (buf[t][p] != 0.f || j == i) {          // mask = adj + I > 0
                const int pos = atomicAdd(&cnt, 1);
                if (pos < MAXN) nbr[pos] = j;
            }
        }
    }
    __syncthreads();
    const int L    = (cnt < MAXN) ? cnt : MAXN;
    const int Lpad = (L + 7) & ~7;                     // multiple of 8 -> Lh multiple of 4
    if (tid < Lpad - L) { nbr[L + tid] = i; wts[L + tid] = 0.f; }  // disjoint from wave0's [0,L)

    // Phase 2 (wave 0 only): s_dst gather -> max -> exp -> sum, all in-wave.
    if (tid < 64) {
        const float ssi = s_src[i];
        float lmax = -1e30f;
        for (int n = tid; n < L; n += 64) {
            const float sd = s_dst[nbr[n]];
            wts[n] = sd;
            lmax = fmaxf(lmax, sd);
        }
#pragma unroll
        for (int off = 32; off > 0; off >>= 1)
            lmax = fmaxf(lmax, __shfl_xor(lmax, off, 64));
        const float Sm  = ssi + lmax;                   // lmax now uniform in wave
        const float m_i = (Sm >= 0.f) ? Sm : 0.2f * Sm;
        float lsum = 0.f;
        for (int n = tid; n < L; n += 64) {
            float S = ssi + wts[n];
            S = (S >= 0.f) ? S : 0.2f * S;
            const float wv = __expf(S - m_i);
            wts[n] = wv;
            lsum += wv;
        }
#pragma unroll
        for (int off = 32; off > 0; off >>= 1) lsum += __shfl_xor(lsum, off, 64);
        if (tid == 0) sinv = 1.f / lsum;
    }
    __syncthreads();                       // publishes wts[], nbr padding, sinv
    const float inv = sinv;

    // Phase 3: h[o] = sum_n w_n * x'[j_n][o]. 2 groups x 4 chains; per-neighbor
    // load is 512B coalesced from L2 (xp = 4MB, L2-resident).
    const int o  = tid & 127;
    const int g  = tid >> 7;
    const int Lh = Lpad >> 1;              // multiple of 4
    const int base = g * Lh;
    const float* xpo = xp + o;
    float h0 = 0.f, h1 = 0.f, h2 = 0.f, h3 = 0.f;
    for (int n = base; n < base + Lh; n += 4) {
        const int   j0 = nbr[n],   j1 = nbr[n+1], j2 = nbr[n+2], j3 = nbr[n+3];
        const float w0 = wts[n],   w1 = wts[n+1], w2 = wts[n+2], w3 = wts[n+3];
        h0 = fmaf(w0, xpo[(size_t)j0 * FOUTc], h0);
        h1 = fmaf(w1, xpo[(size_t)j1 * FOUTc], h1);
        h2 = fmaf(w2, xpo[(size_t)j2 * FOUTc], h2);
        h3 = fmaf(w3, xpo[(size_t)j3 * FOUTc], h3);
    }
    hp[g][o] = (h0 + h1) + (h2 + h3);
    __syncthreads();
    if (tid < FOUTc)
        out[(size_t)i * FOUTc + tid] = (hp[0][tid] + hp[1][tid]) * inv;   // bias in x'
}

extern "C" void kernel_launch(void* const* d_in, const int* in_sizes, int n_in,
                              void* d_out, int out_size, void* d_ws, size_t ws_size,
                              hipStream_t stream)
{
    (void)out_size; (void)ws_size;
    const float* adj  = (const float*)d_in[0];
    const float* x    = (const float*)d_in[1];
    const float* w    = (const float*)d_in[2];
    const float* bias = (const float*)d_in[3];
    const float* phi  = (const float*)d_in[4];
    for (int i = 0; i < n_in; i++) {
        switch (in_sizes[i]) {
            case Nn * Nn:     adj  = (const float*)d_in[i]; break;
            case Nn * FIN:    x    = (const float*)d_in[i]; break;
            case FIN * FOUTc: w    = (const float*)d_in[i]; break;
            case FOUTc:       bias = (const float*)d_in[i]; break;
            case 2 * FOUTc:   phi  = (const float*)d_in[i]; break;
        }
    }
    float* out = (float*)d_out;

    float* xp    = (float*)d_ws;             // 8192 x 128 = 4 MB
    float* s_src = xp + (size_t)Nn * FOUTc;  // 32 KB
    float* s_dst = s_src + Nn;               // 32 KB

    hipLaunchKernelGGL(k_xp,  dim3(256), dim3(256), 0, stream,
                       x, w, bias, phi, xp, s_src, s_dst);
    hipLaunchKernelGGL(k_agg, dim3(Nn),  dim3(256), 0, stream,
                       adj, xp, s_src, s_dst, out);
}